// Round 6
// baseline (37.166 us; speedup 1.0000x reference)
//
#include <hip/hip_runtime.h>
#include <hip/hip_bf16.h>

#define B    64
#define T    4096
#define V    64
#define NQ   64      // NGRAN * NGLIMPSE
#define NHID 2048
#define KDIM 4096    // V * NQ
#define FAN  4097    // KDIM + 1 (l_t column)

#define NT     16    // h columns per gemm block (one MFMA n-tile)
#define SPLITS 8     // K-split across gemm blocks
#define QPB    8     // q per glimpse block (= waves per block)

typedef __attribute__((ext_vector_type(8))) short bf16x8;
typedef __attribute__((ext_vector_type(4))) float f32x4;

static __device__ __forceinline__ short f2bf(float x) {
    union { float f; unsigned u; } c; c.f = x;
    unsigned r = c.u + 0x7fff + ((c.u >> 16) & 1);   // RNE
    return (short)(r >> 16);
}

// ---------------------------------------------------------------------------
// Kernel 1: glimpse interpolation, latency-optimized.
// grid = (B, NQ/QPB), block = 512 (8 waves; wave w -> q = blockIdx.y*8+w,
// lane = v). t row staged in LDS (binary search hits LDS); valid-neighbor
// search via a 32-row windowed bitmask (32 independent coalesced loads, clz/
// ctz) with serial fallback (P ~ 2^-16 per lane-side). Also zeroes out[] for
// the gemm's atomicAdd and writes out2.
// ---------------------------------------------------------------------------
__global__ __launch_bounds__(512) void glimpse_kernel(
    const float* __restrict__ vals, const float* __restrict__ time_,
    const int* __restrict__ masks, const float* __restrict__ l_t,
    unsigned short* __restrict__ g_bf, float* __restrict__ out2,
    float* __restrict__ out)
{
    __shared__ float tlds[T];                      // 16 KB
    __shared__ unsigned short gtile[V][QPB];       // 1 KB
    const int b   = blockIdx.x;
    const int qb  = blockIdx.y;                    // 0..7
    const int tid = threadIdx.x;
    const int v   = tid & 63;
    const int w   = tid >> 6;                      // 0..7
    const int q   = qb * QPB + w;

    // zero this block's slice of out (gemm accumulates later, stream-ordered)
    if (tid < NHID / QPB) out[(size_t)b * NHID + qb * (NHID / QPB) + tid] = 0.0f;

    // stage t[b][:] into LDS, coalesced float4
    {
        const float4* t4  = (const float4*)(time_ + (size_t)b * T);
        float4* tl4 = (float4*)tlds;
        #pragma unroll
        for (int i = 0; i < T / 4 / 512; ++i)
            tl4[tid + i * 512] = t4[tid + i * 512];
    }
    __syncthreads();

    const float tmax = tlds[T - 1];                // times sorted ascending

    const int   j = q & 31;
    const float s = (q < 32) ? 1.0f : 5.0f;
    const float a = 0.5f * 0.1f * s;               // gwidth*s/2
    const float step = (2.0f * a) / 31.0f;
    float lin = (j == 31) ? a : (-a + step * (float)j);
    const float r = (lin + l_t[b]) * tmax;

    // binary search in LDS: p = first index with t[p] > r (wave-uniform)
    int lo = 0, hi = T;
    while (lo < hi) {
        int mid = (lo + hi) >> 1;
        if (tlds[mid] > r) hi = mid; else lo = mid + 1;
    }
    const int p = lo;

    const int* mrow = masks + (size_t)b * T * V + v;

    // 32-row window bitmask: bit j <-> row p-16+j. Independent coalesced loads.
    const int lorow = p - 16;
    unsigned wm = 0;
    #pragma unroll
    for (int jj = 0; jj < 32; ++jj) {
        const int i = lorow + jj;
        int mv = 0;
        if (i >= 0 && i < T) mv = mrow[(size_t)i * V];
        wm |= (mv != 0 ? 1u : 0u) << jj;
    }

    // i0 = largest valid index with t <= r (rows < p); i1 = smallest with t > r
    const unsigned lo16 = wm & 0xffffu;
    const unsigned hi16 = wm >> 16;
    int i0, i1;
    if (lo16) {
        i0 = lorow + (31 - __builtin_clz(lo16));
    } else {
        i0 = -1;
        for (int i = lorow - 1; i >= 0; --i)
            if (mrow[(size_t)i * V] != 0) { i0 = i; break; }
    }
    if (hi16) {
        i1 = p + __builtin_ctz(hi16);
    } else {
        i1 = -1;
        for (int i = p + 16; i < T; ++i)
            if (mrow[(size_t)i * V] != 0) { i1 = i; break; }
    }

    const float* vrow = vals + (size_t)b * T * V + v;
    float y;
    if (i0 < 0 && i1 < 0) {
        y = 0.0f;                                  // no valid points
    } else if (i0 < 0) {
        y = vrow[(size_t)i1 * V];                  // r below first valid
    } else if (i1 < 0) {
        y = vrow[(size_t)i0 * V];                  // r at/above last valid
    } else {
        float t0 = tlds[i0], t1 = tlds[i1];
        float v0 = vrow[(size_t)i0 * V], v1 = vrow[(size_t)i1 * V];
        float den = (t1 > t0) ? (t1 - t0) : 1.0f;
        float ww = (r - t0) / den;
        ww = fminf(fmaxf(ww, 0.0f), 1.0f);
        y = v0 + ww * (v1 - v0);
    }

    gtile[v][w] = (unsigned short)f2bf(y);
    if (v * NQ + q == KDIM / 2) out2[b] = y;       // g[:, 2048], fp32
    __syncthreads();

    // coalesced-ish store: thread d stores row v=d (8 bf16 = 16B contiguous)
    if (tid < V) {
        *(bf16x8*)(g_bf + (size_t)b * KDIM + tid * NQ + qb * QPB) =
            *(const bf16x8*)&gtile[tid][0];
    }
}

// ---------------------------------------------------------------------------
// Kernel 2: MFMA GEMM, K split 8 ways. grid = (NHID/NT, SPLITS) = 1024 blocks
// x 256 thr (4 waves) = 16 waves/CU. Wave owns 128 k = 4 inner iterations.
// LDS-reduce 4 waves, then one atomicAdd per output element per split.
// out was zeroed by glimpse_kernel (stream-ordered before us).
// ---------------------------------------------------------------------------
__global__ __launch_bounds__(256) void gemm_mfma(
    const unsigned short* __restrict__ g_bf, const float* __restrict__ l_t,
    const float* __restrict__ W, const float* __restrict__ bias,
    float* __restrict__ out)
{
    __shared__ float part[4][B][NT];            // 16 KB
    const int lane = threadIdx.x & 63;
    const int wave = threadIdx.x >> 6;
    const int l15  = lane & 15;                 // n (h offset) for B, m for A
    const int lk   = lane >> 4;                 // k-group 0..3
    const int hbase = blockIdx.x * NT;
    const int kbase = blockIdx.y * (KDIM / SPLITS) + wave * (KDIM / SPLITS / 4);

    const float* wrow = W + (size_t)(hbase + l15) * FAN;   // this lane's W row

    f32x4 acc[4];
    #pragma unroll
    for (int mt = 0; mt < 4; ++mt) acc[mt] = (f32x4){0.f, 0.f, 0.f, 0.f};

    #pragma unroll
    for (int ks = 0; ks < KDIM / SPLITS / 4; ks += 32) {
        const int k = kbase + ks + lk * 8;      // this lane's 8 consecutive k

        // B fragment: W[hbase+l15][k .. k+7] fp32 -> bf16
        bf16x8 bfrag;
        #pragma unroll
        for (int e = 0; e < 8; ++e) bfrag[e] = f2bf(wrow[k + e]);

        // A fragments: g[mt*16+l15][k .. k+7] already bf16, 16B aligned
        #pragma unroll
        for (int mt = 0; mt < 4; ++mt) {
            const bf16x8 afrag =
                *(const bf16x8*)(g_bf + (size_t)(mt * 16 + l15) * KDIM + k);
            acc[mt] = __builtin_amdgcn_mfma_f32_16x16x32_bf16(afrag, bfrag, acc[mt], 0, 0, 0);
        }
    }

    // C/D layout: col = lane&15 (h offset), row = (lane>>4)*4 + reg (b in tile)
    #pragma unroll
    for (int mt = 0; mt < 4; ++mt) {
        #pragma unroll
        for (int rreg = 0; rreg < 4; ++rreg) {
            const int b = mt * 16 + lk * 4 + rreg;
            part[wave][b][l15] = acc[mt][rreg];
        }
    }
    __syncthreads();

    for (int o = threadIdx.x; o < B * NT; o += 256) {
        const int b = o >> 4, hoff = o & 15;
        const int h = hbase + hoff;
        float v = part[0][b][hoff] + part[1][b][hoff]
                + part[2][b][hoff] + part[3][b][hoff];
        if (blockIdx.y == 0)
            v += bias[h] + l_t[b] * W[(size_t)h * FAN + KDIM];
        atomicAdd(&out[(size_t)b * NHID + h], v);
    }
}

extern "C" void kernel_launch(void* const* d_in, const int* in_sizes, int n_in,
                              void* d_out, int out_size, void* d_ws, size_t ws_size,
                              hipStream_t stream) {
    const float* vals  = (const float*)d_in[0];
    const float* time_ = (const float*)d_in[1];
    const int*   masks = (const int*)d_in[2];
    // d_in[3] = lengths (all == T, unused)
    const float* l_t   = (const float*)d_in[4];
    const float* W     = (const float*)d_in[5];
    const float* bias  = (const float*)d_in[6];

    float* out  = (float*)d_out;                 // grep [B, NHID]
    float* out2 = out + (size_t)B * NHID;        // g[:, 2048]  [B]
    unsigned short* g_bf = (unsigned short*)d_ws; // bf16 [B][KDIM] = 512 KB

    dim3 g1(B, NQ / QPB);
    glimpse_kernel<<<g1, 512, 0, stream>>>(vals, time_, masks, l_t, g_bf, out2, out);

    dim3 g2(NHID / NT, SPLITS);
    gemm_mfma<<<g2, 256, 0, stream>>>(g_bf, l_t, W, bias, out);
}